// Round 1
// baseline (7496.922 us; speedup 1.0000x reference)
//
#include <hip/hip_runtime.h>
#include <math.h>

#define BATCH 64
#define TT 2048
#define HH 256
#define RR 512          // 2H rows
#define NTHREADS 512
#define REGC 48         // cols held in registers per row
#define LDSC 16         // cols held in LDS per row

// LDS layout (float offsets)
#define WLDS_OFF 0
#define WLDS_SZ  (16*512*4)                 // 32768 floats = 128KB
#define H_OFF    (WLDS_OFF + WLDS_SZ)       // 32768
#define DM_OFF   (H_OFF + 256)              // 33024
#define WIH_OFF  (DM_OFF + 512)             // 33536  [6][512]
#define FCW_OFF  (WIH_OFF + 6*512)          // 36608  [2*256]
#define BIAS_OFF (FCW_OFF + 512)            // 37120  [512]
#define OPART_OFF (BIAS_OFF + 512)          // 37632  [8]
#define SMEM_FLOATS (OPART_OFF + 8)         // 37640 floats = 150560 B

__global__ __launch_bounds__(NTHREADS, 2)
void janet_rnn(const float* __restrict__ x,
               const float* __restrict__ w_ih,
               const float* __restrict__ w_hh,
               const float* __restrict__ b_ih,
               const float* __restrict__ b_hh,
               const float* __restrict__ fc_w,
               const float* __restrict__ fc_b,
               float* __restrict__ out)
{
    extern __shared__ float smem[];
    const int tid = threadIdx.x;
    const int b   = blockIdx.x;
    const int cc  = tid & 3;        // column chunk 0..3 (64 cols each)
    const int rg  = tid >> 2;       // row group 0..127 (4 rows each)
    const int r0  = rg * 4;
    const int c0  = cc * 64;

    float* h_lds    = smem + H_OFF;
    float* dm_lds   = smem + DM_OFF;
    float* wih_lds  = smem + WIH_OFF;
    float* fcw_lds  = smem + FCW_OFF;
    float* bias_lds = smem + BIAS_OFF;
    float* opart    = smem + OPART_OFF;

    // ---------------- init ----------------
    if (tid < 256) h_lds[tid] = 0.0f;     // h_0 is zeros per reference
    if (tid < 8)   opart[tid] = 0.0f;
    bias_lds[tid] = b_ih[tid] + b_hh[tid];
    fcw_lds[tid]  = fc_w[tid];            // [o*256 + i]
    #pragma unroll
    for (int c = 0; c < 6; ++c)
        wih_lds[c*512 + tid] = w_ih[tid*6 + c];   // transpose to [c][r]

    // register-resident W_hh: rows r0..r0+3, cols c0..c0+REGC-1
    float wreg[4][REGC];
    #pragma unroll
    for (int i = 0; i < 4; ++i) {
        #pragma unroll
        for (int j = 0; j < REGC/4; ++j) {
            const float4 v = *reinterpret_cast<const float4*>(
                &w_hh[(r0+i)*256 + c0 + j*4]);
            wreg[i][j*4+0] = v.x; wreg[i][j*4+1] = v.y;
            wreg[i][j*4+2] = v.z; wreg[i][j*4+3] = v.w;
        }
    }
    // LDS-resident W_hh: group g -> row (g>>2), col quad (g&3) of cols [c0+48, c0+64)
    // layout [g][tid][4] so ds_read_b128 is lane-stride-16B (full LDS BW, no conflict)
    #pragma unroll
    for (int g = 0; g < 16; ++g) {
        const int i = g >> 2, q = g & 3;
        const float4 v = *reinterpret_cast<const float4*>(
            &w_hh[(r0+i)*256 + c0 + REGC + q*4]);
        *reinterpret_cast<float4*>(&smem[WLDS_OFF + (g*512 + tid)*4]) = v;
    }
    __syncthreads();

    const float* xb   = x   + (size_t)b * TT * 2;
    float*       outb = out + (size_t)b * TT * 2;
    const float fcb0 = fc_b[0], fcb1 = fc_b[1];

    for (int t = 0; t < TT; ++t) {
        // issue x[t] load early: used only after barrier A (latency hidden)
        float2 xv = make_float2(0.f, 0.f);
        if (tid < 128) xv = *reinterpret_cast<const float2*>(&xb[t*2]);
        // previous step's output projection (opart written last step, barrier'd)
        if (tid == 256 && t > 0) {
            const float o0 = opart[0] + opart[2] + fcb0;
            const float o1 = opart[1] + opart[3] + fcb1;
            *reinterpret_cast<float2*>(&outb[(t-1)*2]) = make_float2(o0, o1);
        }

        // ---- phase 1: partial matvec, 4 rows x 64 cols per thread ----
        float acc0 = 0.f, acc1 = 0.f, acc2 = 0.f, acc3 = 0.f;
        #pragma unroll
        for (int cb = 0; cb < REGC/4; ++cb) {
            const float4 h4 = *reinterpret_cast<const float4*>(&h_lds[c0 + cb*4]);
            acc0 += wreg[0][cb*4+0]*h4.x + wreg[0][cb*4+1]*h4.y
                  + wreg[0][cb*4+2]*h4.z + wreg[0][cb*4+3]*h4.w;
            acc1 += wreg[1][cb*4+0]*h4.x + wreg[1][cb*4+1]*h4.y
                  + wreg[1][cb*4+2]*h4.z + wreg[1][cb*4+3]*h4.w;
            acc2 += wreg[2][cb*4+0]*h4.x + wreg[2][cb*4+1]*h4.y
                  + wreg[2][cb*4+2]*h4.z + wreg[2][cb*4+3]*h4.w;
            acc3 += wreg[3][cb*4+0]*h4.x + wreg[3][cb*4+1]*h4.y
                  + wreg[3][cb*4+2]*h4.z + wreg[3][cb*4+3]*h4.w;
        }
        #pragma unroll
        for (int q = 0; q < 4; ++q) {
            const float4 h4 = *reinterpret_cast<const float4*>(&h_lds[c0 + REGC + q*4]);
            {
                const float4 w4 = *reinterpret_cast<const float4*>(
                    &smem[WLDS_OFF + ((0*4+q)*512 + tid)*4]);
                acc0 += w4.x*h4.x + w4.y*h4.y + w4.z*h4.z + w4.w*h4.w;
            }
            {
                const float4 w4 = *reinterpret_cast<const float4*>(
                    &smem[WLDS_OFF + ((1*4+q)*512 + tid)*4]);
                acc1 += w4.x*h4.x + w4.y*h4.y + w4.z*h4.z + w4.w*h4.w;
            }
            {
                const float4 w4 = *reinterpret_cast<const float4*>(
                    &smem[WLDS_OFF + ((2*4+q)*512 + tid)*4]);
                acc2 += w4.x*h4.x + w4.y*h4.y + w4.z*h4.z + w4.w*h4.w;
            }
            {
                const float4 w4 = *reinterpret_cast<const float4*>(
                    &smem[WLDS_OFF + ((3*4+q)*512 + tid)*4]);
                acc3 += w4.x*h4.x + w4.y*h4.y + w4.z*h4.z + w4.w*h4.w;
            }
        }
        // reduce the 4 column-chunks (lanes cc = tid&3, xor 1 then 2)
        acc0 += __shfl_xor(acc0, 1); acc0 += __shfl_xor(acc0, 2);
        acc1 += __shfl_xor(acc1, 1); acc1 += __shfl_xor(acc1, 2);
        acc2 += __shfl_xor(acc2, 1); acc2 += __shfl_xor(acc2, 2);
        acc3 += __shfl_xor(acc3, 1); acc3 += __shfl_xor(acc3, 2);
        if (cc == 0) {
            *reinterpret_cast<float4*>(&dm_lds[r0]) =
                make_float4(acc0, acc1, acc2, acc3);
        }
        __syncthreads();   // barrier A: dm ready

        // ---- phase 3: gates + h update (threads 0..127, 2 rows each) ----
        if (tid < 128) {
            const int i0 = tid * 2;
            const float ix = xv.x, qx = xv.y;
            const float amp  = sqrtf(ix*ix + qx*qx);
            const float amp3 = amp * amp * amp;
            const float fe0 = ix, fe1 = qx, fe2 = amp, fe3 = amp3;
            const float fe4 = qx / amp;   // sin
            const float fe5 = ix / amp;   // cos
            const float fe[6] = { fe0, fe1, fe2, fe3, fe4, fe5 };

            float dmf0 = dm_lds[i0]     + bias_lds[i0];
            float dmf1 = dm_lds[i0+1]   + bias_lds[i0+1];
            float dmg0 = dm_lds[i0+256] + bias_lds[i0+256];
            float dmg1 = dm_lds[i0+257] + bias_lds[i0+257];
            #pragma unroll
            for (int c = 0; c < 6; ++c) {
                const float2 wf = *reinterpret_cast<const float2*>(&wih_lds[c*512 + i0]);
                const float2 wg = *reinterpret_cast<const float2*>(&wih_lds[c*512 + 256 + i0]);
                dmf0 += wf.x * fe[c]; dmf1 += wf.y * fe[c];
                dmg0 += wg.x * fe[c]; dmg1 += wg.y * fe[c];
            }
            const float gf0 = 1.0f / (1.0f + __expf(-dmf0));
            const float gf1 = 1.0f / (1.0f + __expf(-dmf1));
            const float gg0 = 1.0f / (1.0f + __expf(-dmg0));
            const float gg1 = 1.0f / (1.0f + __expf(-dmg1));
            const float2 ho = *reinterpret_cast<const float2*>(&h_lds[i0]);
            const float hn0 = (1.0f - gf0) * gg0 + gf0 * ho.x;
            const float hn1 = (1.0f - gf1) * gg1 + gf1 * ho.y;
            *reinterpret_cast<float2*>(&h_lds[i0]) = make_float2(hn0, hn1);

            // output projection partials + in-wave butterfly
            const float2 w0 = *reinterpret_cast<const float2*>(&fcw_lds[i0]);
            const float2 w1 = *reinterpret_cast<const float2*>(&fcw_lds[256 + i0]);
            float po0 = w0.x*hn0 + w0.y*hn1;
            float po1 = w1.x*hn0 + w1.y*hn1;
            #pragma unroll
            for (int s = 1; s < 64; s <<= 1) {
                po0 += __shfl_xor(po0, s);
                po1 += __shfl_xor(po1, s);
            }
            if ((tid & 63) == 0) {
                opart[(tid >> 6)*2 + 0] = po0;
                opart[(tid >> 6)*2 + 1] = po1;
            }
        }
        __syncthreads();   // barrier B: h(t) + opart ready
    }
    // final timestep's output
    if (tid == 256) {
        const float o0 = opart[0] + opart[2] + fcb0;
        const float o1 = opart[1] + opart[3] + fcb1;
        *reinterpret_cast<float2*>(&outb[(TT-1)*2]) = make_float2(o0, o1);
    }
}

extern "C" void kernel_launch(void* const* d_in, const int* in_sizes, int n_in,
                              void* d_out, int out_size, void* d_ws, size_t ws_size,
                              hipStream_t stream) {
    const float* x    = (const float*)d_in[0];
    // d_in[1] = h_0 : ignored by the reference (it uses zeros)
    const float* w_ih = (const float*)d_in[2];
    const float* w_hh = (const float*)d_in[3];
    const float* b_ih = (const float*)d_in[4];
    const float* b_hh = (const float*)d_in[5];
    const float* fc_w = (const float*)d_in[6];
    const float* fc_b = (const float*)d_in[7];
    float* out = (float*)d_out;

    const size_t smem_bytes = SMEM_FLOATS * sizeof(float);   // ~147 KB
    hipFuncSetAttribute((const void*)janet_rnn,
                        hipFuncAttributeMaxDynamicSharedMemorySize,
                        (int)smem_bytes);
    hipLaunchKernelGGL(janet_rnn, dim3(BATCH), dim3(NTHREADS), smem_bytes, stream,
                       x, w_ih, w_hh, b_ih, b_hh, fc_w, fc_b, out);
}

// Round 2
// 2444.829 us; speedup vs baseline: 3.0664x; 3.0664x over previous
//
#include <hip/hip_runtime.h>
#include <math.h>

typedef _Float16 half2v __attribute__((ext_vector_type(2)));

#define TT 2048
#define HP 36   // padded dwords per 32-dword h-chunk (breaks bank clustering)

#if __has_builtin(__builtin_amdgcn_fdot2)
#define FDOT2(a,b,c) __builtin_amdgcn_fdot2((a),(b),(c),false)
#else
#define FDOT2(a,b,c) ((c) + (float)(a).x*(float)(b).x + (float)(a).y*(float)(b).y)
#endif

__global__ __launch_bounds__(512)
__attribute__((amdgpu_waves_per_eu(2, 2)))
void janet_rnn(const float* __restrict__ x,
               const float* __restrict__ w_ih,
               const float* __restrict__ w_hh,
               const float* __restrict__ b_ih,
               const float* __restrict__ b_hh,
               const float* __restrict__ fc_w,
               const float* __restrict__ fc_b,
               float* __restrict__ out)
{
    __shared__ unsigned int hbuf[2][4 * HP];   // ping-pong packed-f16 h (padded chunks)
    __shared__ float dm[512];
    __shared__ float wih[6][512];
    __shared__ float biasv[512];

    const int tid = threadIdx.x;
    const int b   = blockIdx.x;
    const int cc  = tid & 3;        // column chunk 0..3 (64 h-cols each)
    const int rg  = tid >> 2;       // row group 0..127
    const int r0  = rg * 4;
    const int c0  = cc * 64;

    // ---------------- init ----------------
    if (tid < 4 * HP) { hbuf[0][tid] = 0u; hbuf[1][tid] = 0u; }
    biasv[tid] = b_ih[tid] + b_hh[tid];
    #pragma unroll
    for (int c = 0; c < 6; ++c) wih[c][tid] = w_ih[tid * 6 + c];   // [c][r]

    // W_hh fragment: rows r0..r0+3 x cols c0..c0+63, packed f16 (RTN), register-resident
    half2v wp[4][32];
    #pragma unroll
    for (int i = 0; i < 4; ++i) {
        const float* wr = w_hh + (r0 + i) * 256 + c0;
        #pragma unroll
        for (int j = 0; j < 16; ++j) {
            const float4 v = *reinterpret_cast<const float4*>(wr + j * 4);
            half2v p0; p0.x = (_Float16)v.x; p0.y = (_Float16)v.y;
            half2v p1; p1.x = (_Float16)v.z; p1.y = (_Float16)v.w;
            wp[i][j * 2 + 0] = p0;
            wp[i][j * 2 + 1] = p1;
        }
    }

    // projection wave (tids 256..319): fc_w fragment in registers
    const int pl = tid - 256;
    float fw[8];
    if (pl >= 0 && pl < 64) {
        #pragma unroll
        for (int k = 0; k < 4; ++k) {
            fw[k]     = fc_w[pl * 4 + k];
            fw[4 + k] = fc_w[256 + pl * 4 + k];
        }
    }
    const float fcb0 = fc_b[0], fcb1 = fc_b[1];

    float hreg = 0.0f;   // phase-3 thread's own h element (tid<256), h_0 = 0

    const float* xb   = x   + (size_t)b * TT * 2;
    float*       outb = out + (size_t)b * TT * 2;

    __syncthreads();

    #pragma unroll 1
    for (int t = 0; t < TT; ++t) {
        // prefetch x[t] (same 8B for all phase-3 threads; latency hides under matvec)
        float xi = 0.f, xq = 0.f;
        if (tid < 256) {
            const float2 xv = *reinterpret_cast<const float2*>(xb + 2 * t);
            xi = xv.x; xq = xv.y;
        }

        // ---- matvec: dm = W_hh @ h_{t-1}  (h in hbuf[(t+1)&1]) ----
        const unsigned int* hb = &hbuf[(t + 1) & 1][cc * HP];
        half2v hr[32];
        #pragma unroll
        for (int q = 0; q < 8; ++q) {
            const uint4 r = *reinterpret_cast<const uint4*>(hb + 4 * q);
            hr[q * 4 + 0] = __builtin_bit_cast(half2v, r.x);
            hr[q * 4 + 1] = __builtin_bit_cast(half2v, r.y);
            hr[q * 4 + 2] = __builtin_bit_cast(half2v, r.z);
            hr[q * 4 + 3] = __builtin_bit_cast(half2v, r.w);
        }
        float a0 = 0.f, a1 = 0.f, a2 = 0.f, a3 = 0.f;
        #pragma unroll
        for (int j = 0; j < 32; ++j) {
            a0 = FDOT2(wp[0][j], hr[j], a0);
            a1 = FDOT2(wp[1][j], hr[j], a1);
            a2 = FDOT2(wp[2][j], hr[j], a2);
            a3 = FDOT2(wp[3][j], hr[j], a3);
        }
        // reduce the 4 column-chunks (lanes cc, xor 1 then 2)
        a0 += __shfl_xor(a0, 1); a0 += __shfl_xor(a0, 2);
        a1 += __shfl_xor(a1, 1); a1 += __shfl_xor(a1, 2);
        a2 += __shfl_xor(a2, 1); a2 += __shfl_xor(a2, 2);
        a3 += __shfl_xor(a3, 1); a3 += __shfl_xor(a3, 2);
        if (cc == 0)
            *reinterpret_cast<float4*>(&dm[r0]) = make_float4(a0, a1, a2, a3);
        __syncthreads();   // barrier A: dm ready

        if (tid < 256) {
            // ---- phase 3: gates + h update, 1 element/thread ----
            const float amp  = sqrtf(xi * xi + xq * xq);
            const float amp3 = amp * amp * amp;
            const float snv  = xq / amp;
            const float csv  = xi / amp;
            float dmf = dm[tid]       + biasv[tid];
            float dmg = dm[256 + tid] + biasv[256 + tid];
            dmf += wih[0][tid] * xi  + wih[1][tid] * xq  + wih[2][tid] * amp
                 + wih[3][tid] * amp3 + wih[4][tid] * snv + wih[5][tid] * csv;
            dmg += wih[0][256 + tid] * xi  + wih[1][256 + tid] * xq
                 + wih[2][256 + tid] * amp + wih[3][256 + tid] * amp3
                 + wih[4][256 + tid] * snv + wih[5][256 + tid] * csv;
            const float gf = 1.0f / (1.0f + __expf(-dmf));
            const float gg = 1.0f / (1.0f + __expf(-dmg));
            hreg = (1.0f - gf) * gg + gf * hreg;
            // pack pair (even lane packs self + odd neighbor), conflict-free b32 write
            const float hhi = __shfl_down(hreg, 1);
            if ((tid & 1) == 0) {
                half2v hp2; hp2.x = (_Float16)hreg; hp2.y = (_Float16)hhi;
                const int c = tid >> 6;
                const int i = (tid >> 1) & 31;
                hbuf[t & 1][c * HP + i] = __builtin_bit_cast(unsigned int, hp2);
            }
        } else if (pl < 64 && t > 0) {
            // ---- projection wave: out[t-1] = fc_w @ h_{t-1} + fc_b (off critical path)
            const unsigned int* hp = hbuf[(t + 1) & 1];
            const int c = pl >> 4;
            const int i = (2 * pl) & 31;
            const unsigned int u0 = hp[c * HP + i];
            const unsigned int u1 = hp[c * HP + i + 1];
            const half2v ha = __builtin_bit_cast(half2v, u0);
            const half2v hc = __builtin_bit_cast(half2v, u1);
            const float h0v = (float)ha.x, h1v = (float)ha.y;
            const float h2v = (float)hc.x, h3v = (float)hc.y;
            float po0 = fw[0] * h0v + fw[1] * h1v + fw[2] * h2v + fw[3] * h3v;
            float po1 = fw[4] * h0v + fw[5] * h1v + fw[6] * h2v + fw[7] * h3v;
            #pragma unroll
            for (int s = 1; s < 64; s <<= 1) {
                po0 += __shfl_xor(po0, s);
                po1 += __shfl_xor(po1, s);
            }
            if (pl == 0)
                *reinterpret_cast<float2*>(outb + (t - 1) * 2) =
                    make_float2(po0 + fcb0, po1 + fcb1);
        }
        __syncthreads();   // barrier B: h_t packed & visible
    }

    // final projection: h_{TT-1} lives in hbuf[(TT-1)&1]
    if (pl >= 0 && pl < 64) {
        const unsigned int* hp = hbuf[(TT - 1) & 1];
        const int c = pl >> 4;
        const int i = (2 * pl) & 31;
        const unsigned int u0 = hp[c * HP + i];
        const unsigned int u1 = hp[c * HP + i + 1];
        const half2v ha = __builtin_bit_cast(half2v, u0);
        const half2v hc = __builtin_bit_cast(half2v, u1);
        const float h0v = (float)ha.x, h1v = (float)ha.y;
        const float h2v = (float)hc.x, h3v = (float)hc.y;
        float po0 = fw[0] * h0v + fw[1] * h1v + fw[2] * h2v + fw[3] * h3v;
        float po1 = fw[4] * h0v + fw[5] * h1v + fw[6] * h2v + fw[7] * h3v;
        #pragma unroll
        for (int s = 1; s < 64; s <<= 1) {
            po0 += __shfl_xor(po0, s);
            po1 += __shfl_xor(po1, s);
        }
        if (pl == 0)
            *reinterpret_cast<float2*>(outb + (TT - 1) * 2) =
                make_float2(po0 + fcb0, po1 + fcb1);
    }
}

extern "C" void kernel_launch(void* const* d_in, const int* in_sizes, int n_in,
                              void* d_out, int out_size, void* d_ws, size_t ws_size,
                              hipStream_t stream) {
    (void)in_sizes; (void)n_in; (void)out_size; (void)d_ws; (void)ws_size;
    const float* x    = (const float*)d_in[0];
    // d_in[1] = h_0 : reference ignores it (uses zeros)
    const float* w_ih = (const float*)d_in[2];
    const float* w_hh = (const float*)d_in[3];
    const float* b_ih = (const float*)d_in[4];
    const float* b_hh = (const float*)d_in[5];
    const float* fc_w = (const float*)d_in[6];
    const float* fc_b = (const float*)d_in[7];
    float* outp = (float*)d_out;

    hipLaunchKernelGGL(janet_rnn, dim3(64), dim3(512), 0, stream,
                       x, w_ih, w_hh, b_ih, b_hh, fc_w, fc_b, outp);
}